// Round 3
// baseline (214.903 us; speedup 1.0000x reference)
//
#include <hip/hip_runtime.h>

// GCN 2-layer, R16 = R15 + software-pipelined edge gather in gemm_fused:
// 2-edge x 2-stage ping-pong (A/B reg sets), col indices prefetched one
// iteration ahead and issued FIRST in the body so steady state never hits
// vmcnt(0) - 16-20 loads in flight/lane, col and row latency both hidden.
// R15 evidence: compiler chose 64 VGPR under a 128 cap -> only ~5 loads ever
// in flight; chain col->addr->rows->acc exposed 2 round trips per batch.
//   wswz(+ctrl zero) | bin | bucket_csr(dinv,Xs) | gemm_fused | gather2
// Lessons: no global atomic work queues (R7); no serial straggler blocks (R9);
// zero ALL control memory (R11); min-waves must fit live regs or spills eat
// 3x (R14); compiler won't deepen load pipelines on its own - write the
// ping-pong at source (R15).

typedef short bf16x8 __attribute__((ext_vector_type(8)));
typedef float f32x4 __attribute__((ext_vector_type(4)));

#define LDSTRIDE 264   // 16 rows * 264 bf16 = 528 B/row: b128-aligned
#define BSHIFT 7       // 128 dsts per bucket
#define BMASK 127

__device__ inline unsigned short f2bf(float f) {          // RNE
    unsigned int u = __float_as_uint(f);
    u += 0x7FFF + ((u >> 16) & 1);
    return (unsigned short)(u >> 16);
}
__device__ inline float bf2f(unsigned short h) {
    return __uint_as_float(((unsigned int)h) << 16);
}

// ---------- W swizzle into MFMA b-frag order + ctrl zero ----------
__device__ inline void swz1(const float* W, unsigned short* Ws, int K, int N, int i) {
    int k = i / N, n = i % N;
    int KC = K >> 5;
    size_t d = ((((size_t)(n >> 4) * KC + (k >> 5)) * 64) + ((k >> 3) & 3) * 16 + (n & 15)) * 8
               + (k & 7);
    Ws[d] = f2bf(W[i]);
}
__global__ void wswz_kernel(const float* __restrict__ W1, const float* __restrict__ W2,
                            unsigned short* __restrict__ W1s, unsigned short* __restrict__ W2s,
                            int* __restrict__ ctrl) {
    int i = blockIdx.x * blockDim.x + threadIdx.x;
    if (blockIdx.x == 0) {                     // zero ALL 512 ctrl ints
        for (int j = threadIdx.x; j < 512; j += 256) ctrl[j] = 0;
    }
    if (i < 32768) swz1(W1, W1s, 128, 256, i);
    else if (i < 65536) swz1(W2, W2s, 256, 128, i - 32768);
}

// ---------- pass 1: bin edges by dst>>7 (4 B packed) ----------
__global__ __launch_bounds__(256) void bin_kernel(
    const int* __restrict__ src, const int* __restrict__ dst,
    int* __restrict__ bcur, unsigned int* __restrict__ bbuf,
    int E, int cap, int nbuck) {
    __shared__ int cnt[512];
    __shared__ int base[512];
    int t = threadIdx.x;
    for (int i = t; i < nbuck; i += 256) cnt[i] = 0;
    __syncthreads();
    int e0 = blockIdx.x * 2048;
    unsigned int p_[8];
    int b_[8];
#pragma unroll
    for (int i = 0; i < 8; i++) {
        int e = e0 + i * 256 + t;
        if (e < E) {
            int s = src[e], d = dst[e];
            b_[i] = d >> BSHIFT;
            p_[i] = ((unsigned)(d & BMASK) << 24) | (unsigned)s;   // N < 2^24
            atomicAdd(&cnt[b_[i]], 1);
        } else b_[i] = -1;
    }
    __syncthreads();
    for (int b = t; b < nbuck; b += 256) {
        int c = cnt[b];
        base[b] = (c > 0) ? atomicAdd(&bcur[b], c) : 0;
    }
    __syncthreads();
    for (int i = t; i < nbuck; i += 256) cnt[i] = 0;   // reuse as cursor
    __syncthreads();
#pragma unroll
    for (int i = 0; i < 8; i++) {
        if (b_[i] >= 0) {
            int b = b_[i];
            int p = base[b] + atomicAdd(&cnt[b], 1);
            if (p >= 0 && p < cap) bbuf[(size_t)b * cap + p] = p_[i];
        }
    }
}

// ---------- pass 2: per-bucket (128 dsts) CSR + dinv + fused Xs ----------
__global__ __launch_bounds__(256) void bucket_csr_kernel(
    const int* __restrict__ bcur, const unsigned int* __restrict__ bbuf,
    const float* __restrict__ x,
    int* __restrict__ col, int* __restrict__ rowbeg, int* __restrict__ rowend,
    float* __restrict__ dinv, unsigned short* __restrict__ Xs, int N, int cap) {
    __shared__ int ldeg[128];
    __shared__ int lrp[256];
    __shared__ float sdv[128];
    int b = blockIdx.x, t = threadIdx.x;
    int cnt = min(max(bcur[b], 0), cap);
    if (t < 128) ldeg[t] = 0;
    __syncthreads();
    const unsigned int* mybuf = bbuf + (size_t)b * cap;
    for (int i = t; i < cnt; i += 256)
        atomicAdd(&ldeg[mybuf[i] >> 24], 1);
    __syncthreads();
    int v = (t < 128) ? ldeg[t] : 0;
    lrp[t] = v;
    __syncthreads();
    for (int off = 1; off < 128; off <<= 1) {    // inclusive scan (128 live)
        int u = (t >= off) ? lrp[t - off] : 0;
        __syncthreads();
        lrp[t] += u;
        __syncthreads();
    }
    int excl = lrp[t] - v;
    int gbase = b * cap;
    if (t < 128) {
        int r = b * 128 + t;
        float dv = rsqrtf((float)v + 1.0f);      // self-loop adds 1
        sdv[t] = dv;
        if (r < N) {
            rowbeg[r] = gbase + excl;
            rowend[r] = gbase + excl + v;
            dinv[r] = dv;
        }
        ldeg[t] = excl;    // reuse as cursor
    }
    __syncthreads();
    for (int i = t; i < cnt; i += 256) {
        unsigned int pr = mybuf[i];
        int p = atomicAdd(&ldeg[pr >> 24], 1);
        col[gbase + p] = (int)(pr & 0xffffffu);
    }
    // fused Xs: rows b*128..+127, coalesced ushort4
    int rbase = b * 128;
    for (int i = t; i < 128 * 32; i += 256) {
        int rl = i >> 5;
        int gr = rbase + rl;
        if (gr >= N) break;
        float s = sdv[rl];
        float4 xv = ((const float4*)x)[(size_t)gr * 32 + (i & 31)];
        ushort4 o;
        o.x = f2bf(xv.x * s); o.y = f2bf(xv.y * s);
        o.z = f2bf(xv.z * s); o.w = f2bf(xv.w * s);
        ((ushort4*)Xs)[(size_t)gr * 32 + (i & 31)] = o;
    }
}

// ---------- gather2: half-wave per row, ushort4/lane, unroll x8, fused epi ----------
__global__ __launch_bounds__(256) void gather2_kernel(
    const int* __restrict__ rowbeg, const int* __restrict__ rowend,
    const int* __restrict__ col, const unsigned short* __restrict__ P,
    const float* __restrict__ dinv, const float* __restrict__ bias,
    float* __restrict__ OF, int N) {
    int gid = blockIdx.x * blockDim.x + threadIdx.x;
    int r = gid >> 5;
    if (r >= N) return;
    int lane = gid & 31;
    const size_t off = (size_t)lane * 4;
    const unsigned short* Pf = P + off;

    ushort4 u = *(const ushort4*)(Pf + (size_t)r * 128);
    float ax = bf2f(u.x), ay = bf2f(u.y), az = bf2f(u.z), aw = bf2f(u.w);

    int beg = rowbeg[r], end = rowend[r];
    int i = beg;
    for (; i + 7 < end; i += 8) {
        ushort4 v0 = *(const ushort4*)(Pf + (size_t)col[i + 0] * 128);
        ushort4 v1 = *(const ushort4*)(Pf + (size_t)col[i + 1] * 128);
        ushort4 v2 = *(const ushort4*)(Pf + (size_t)col[i + 2] * 128);
        ushort4 v3 = *(const ushort4*)(Pf + (size_t)col[i + 3] * 128);
        ushort4 v4 = *(const ushort4*)(Pf + (size_t)col[i + 4] * 128);
        ushort4 v5 = *(const ushort4*)(Pf + (size_t)col[i + 5] * 128);
        ushort4 v6 = *(const ushort4*)(Pf + (size_t)col[i + 6] * 128);
        ushort4 v7 = *(const ushort4*)(Pf + (size_t)col[i + 7] * 128);
        ax += bf2f(v0.x) + bf2f(v1.x) + bf2f(v2.x) + bf2f(v3.x)
            + bf2f(v4.x) + bf2f(v5.x) + bf2f(v6.x) + bf2f(v7.x);
        ay += bf2f(v0.y) + bf2f(v1.y) + bf2f(v2.y) + bf2f(v3.y)
            + bf2f(v4.y) + bf2f(v5.y) + bf2f(v6.y) + bf2f(v7.y);
        az += bf2f(v0.z) + bf2f(v1.z) + bf2f(v2.z) + bf2f(v3.z)
            + bf2f(v4.z) + bf2f(v5.z) + bf2f(v6.z) + bf2f(v7.z);
        aw += bf2f(v0.w) + bf2f(v1.w) + bf2f(v2.w) + bf2f(v3.w)
            + bf2f(v4.w) + bf2f(v5.w) + bf2f(v6.w) + bf2f(v7.w);
    }
    for (; i < end; i++) {
        ushort4 a = *(const ushort4*)(Pf + (size_t)col[i] * 128);
        ax += bf2f(a.x); ay += bf2f(a.y); az += bf2f(a.z); aw += bf2f(a.w);
    }
    float s = dinv[r];
    float4 bb = *(const float4*)(bias + off);
    float4 o;
    o.x = fmaxf(ax * s + bb.x, 0.f);
    o.y = fmaxf(ay * s + bb.y, 0.f);
    o.z = fmaxf(az * s + bb.z, 0.f);
    o.w = fmaxf(aw * s + bb.w, 0.f);
    *(float4*)(OF + (size_t)r * 128 + off) = o;
}

// ---------- fused gather1 + GEMM1 + GEMM2, 2 waves per 16-row tile ----------
// Edge gather is a 2-stage software pipeline (A/B), 2 edges per stage, with
// col indices prefetched one iteration ahead. Body order: issue next cols
// FIRST, then ACC(A)+refill, ACC(B)+refill -> the compiler's vmcnt for ACC(A)
// leaves B + new cols in flight; no vmcnt(0) in steady state.
#define ISSUE2(P0, P1, P2, P3, Q0, Q1, Q2, Q3, r0, r1)                          \
    do {                                                                        \
        size_t o0_ = (size_t)(r0) * 128, o1_ = (size_t)(r1) * 128;              \
        P0 = *(const bf16x8*)(base + o0_);                                      \
        P1 = *(const bf16x8*)(base + o0_ + 32);                                 \
        P2 = *(const bf16x8*)(base + o0_ + 64);                                 \
        P3 = *(const bf16x8*)(base + o0_ + 96);                                 \
        Q0 = *(const bf16x8*)(base + o1_);                                      \
        Q1 = *(const bf16x8*)(base + o1_ + 32);                                 \
        Q2 = *(const bf16x8*)(base + o1_ + 64);                                 \
        Q3 = *(const bf16x8*)(base + o1_ + 96);                                 \
    } while (0)

#define ACC2(P0, P1, P2, P3, Q0, Q1, Q2, Q3)                                    \
    do {                                                                        \
        _Pragma("unroll") for (int j_ = 0; j_ < 8; j_++) {                      \
            acc[0][j_] += bf2f((unsigned short)P0[j_]) + bf2f((unsigned short)Q0[j_]); \
            acc[1][j_] += bf2f((unsigned short)P1[j_]) + bf2f((unsigned short)Q1[j_]); \
            acc[2][j_] += bf2f((unsigned short)P2[j_]) + bf2f((unsigned short)Q2[j_]); \
            acc[3][j_] += bf2f((unsigned short)P3[j_]) + bf2f((unsigned short)Q3[j_]); \
        }                                                                       \
    } while (0)

__global__ __launch_bounds__(128, 3) void gemm_fused_kernel(
    const int* __restrict__ rowbeg, const int* __restrict__ rowend,
    const int* __restrict__ col, const unsigned short* __restrict__ Xs,
    const unsigned short* __restrict__ W1s, const unsigned short* __restrict__ W2s,
    const float* __restrict__ bias, const float* __restrict__ dinv,
    unsigned short* __restrict__ T, int M) {
    __shared__ unsigned short afr[16 * 136];   // 4352 B: bf16 a-frags (wave0 -> wave1)
    __shared__ float part[16 * 132];           // 8448 B: f32 partial, then H tile (alias)
    unsigned short* Hl = (unsigned short*)part;   // 16 rows x LDSTRIDE(264) ushort

    int wave = threadIdx.x >> 6;
    int lane = threadIdx.x & 63;
    int m0 = blockIdx.x * 16;
    int mrow = lane & 15, quad = lane >> 4;

    int rr = m0 + mrow; if (rr >= M) rr = M - 1;
    float acc[4][8];
    const unsigned short* base = Xs + quad * 8;
    int beg = rowbeg[rr], end = rowend[rr];
    int half = (end - beg) >> 1;               // wave0 gets floor half (+ self term)
    int b0 = wave ? (beg + half) : beg;
    int e0 = wave ? end : (beg + half);

    if (wave == 0) {                           // self-loop contribution
#pragma unroll
        for (int kc = 0; kc < 4; kc++) {
            bf16x8 v = *(const bf16x8*)(base + (size_t)rr * 128 + kc * 32);
#pragma unroll
            for (int j = 0; j < 8; j++) acc[kc][j] = bf2f((unsigned short)v[j]);
        }
    } else {
#pragma unroll
        for (int kc = 0; kc < 4; kc++)
#pragma unroll
            for (int j = 0; j < 8; j++) acc[kc][j] = 0.f;
    }

    {   // ---- pipelined gather over this wave's edge half ----
        int cnt = e0 - b0;
        int n2 = cnt >> 1;
        int cl = e0 - 1;                        // clamp for speculative col reads
        bf16x8 A00, A01, A02, A03, A10, A11, A12, A13;
        bf16x8 B00, B01, B02, B03, B10, B11, B12, B13;
        if (n2 >= 2) {
            int a0 = col[b0], a1 = col[b0 + 1];
            int c0 = col[b0 + 2], c1 = col[b0 + 3];
            ISSUE2(A00, A01, A02, A03, A10, A11, A12, A13, a0, a1);
            ISSUE2(B00, B01, B02, B03, B10, B11, B12, B13, c0, c1);
            int issued = 2;
            int q = b0 + 4;
            int p0 = q,     p1 = q + 1, p2 = q + 2, p3 = q + 3;
            int na0 = col[p0 < cl ? p0 : cl], na1 = col[p1 < cl ? p1 : cl];
            int nb0 = col[p2 < cl ? p2 : cl], nb1 = col[p3 < cl ? p3 : cl];
            q += 4;
            while (issued + 2 <= n2) {
                int t0 = q, t1 = q + 1, t2 = q + 2, t3 = q + 3;
                int ta0 = col[t0 < cl ? t0 : cl], ta1 = col[t1 < cl ? t1 : cl];
                int tb0 = col[t2 < cl ? t2 : cl], tb1 = col[t3 < cl ? t3 : cl];
                q += 4;
                ACC2(A00, A01, A02, A03, A10, A11, A12, A13);
                ISSUE2(A00, A01, A02, A03, A10, A11, A12, A13, na0, na1);
                ACC2(B00, B01, B02, B03, B10, B11, B12, B13);
                ISSUE2(B00, B01, B02, B03, B10, B11, B12, B13, nb0, nb1);
                issued += 2;
                na0 = ta0; na1 = ta1; nb0 = tb0; nb1 = tb1;
            }
            if (issued < n2) {   // one leftover batch; its cols already in na
                ACC2(A00, A01, A02, A03, A10, A11, A12, A13);
                ISSUE2(A00, A01, A02, A03, A10, A11, A12, A13, na0, na1);
                ACC2(B00, B01, B02, B03, B10, B11, B12, B13);
                ACC2(A00, A01, A02, A03, A10, A11, A12, A13);
            } else {
                ACC2(A00, A01, A02, A03, A10, A11, A12, A13);
                ACC2(B00, B01, B02, B03, B10, B11, B12, B13);
            }
        } else if (n2 == 1) {
            int a0 = col[b0], a1 = col[b0 + 1];
            ISSUE2(A00, A01, A02, A03, A10, A11, A12, A13, a0, a1);
            ACC2(A00, A01, A02, A03, A10, A11, A12, A13);
        }
        if (cnt & 1) {                           // odd tail edge at e0-1
            size_t c0 = (size_t)col[e0 - 1] * 128;
#pragma unroll
            for (int kc = 0; kc < 4; kc++) {
                bf16x8 p = *(const bf16x8*)(base + c0 + kc * 32);
#pragma unroll
                for (int j = 0; j < 8; j++) acc[kc][j] += bf2f((unsigned short)p[j]);
            }
        }
    }

    // ---- cross-wave combine: wave1 partial -> LDS; wave0 adds + makes a-frags ----
    if (wave == 1) {
#pragma unroll
        for (int kc = 0; kc < 4; kc++) {
            f32x4 lo = {acc[kc][0], acc[kc][1], acc[kc][2], acc[kc][3]};
            f32x4 hi = {acc[kc][4], acc[kc][5], acc[kc][6], acc[kc][7]};
            *(f32x4*)(part + mrow * 132 + kc * 32 + quad * 8) = lo;
            *(f32x4*)(part + mrow * 132 + kc * 32 + quad * 8 + 4) = hi;
        }
    }
    __syncthreads();
    bf16x8 a[4];
    if (wave == 0) {
        float dvr = dinv[rr];
#pragma unroll
        for (int kc = 0; kc < 4; kc++) {
            f32x4 lo = *(const f32x4*)(part + mrow * 132 + kc * 32 + quad * 8);
            f32x4 hi = *(const f32x4*)(part + mrow * 132 + kc * 32 + quad * 8 + 4);
#pragma unroll
            for (int j = 0; j < 4; j++) {
                a[kc][j]     = (short)f2bf((acc[kc][j]     + lo[j]) * dvr);
                a[kc][j + 4] = (short)f2bf((acc[kc][j + 4] + hi[j]) * dvr);
            }
            *(bf16x8*)(afr + mrow * 136 + kc * 32 + quad * 8) = a[kc];
        }
    }
    __syncthreads();
    if (wave == 1) {
#pragma unroll
        for (int kc = 0; kc < 4; kc++)
            a[kc] = *(const bf16x8*)(afr + mrow * 136 + kc * 32 + quad * 8);
    }

    // ---- GEMM1: H tile -> LDS, nt range split by wave ----
    float dv[4];
#pragma unroll
    for (int i2 = 0; i2 < 4; i2++) {
        int gr = m0 + quad * 4 + i2;
        dv[i2] = dinv[gr < M ? gr : M - 1];
    }
    const bf16x8* w1v = (const bf16x8*)W1s;
    for (int nt = wave * 8; nt < wave * 8 + 8; nt++) {
        f32x4 c = {0.f, 0.f, 0.f, 0.f};
#pragma unroll
        for (int kc = 0; kc < 4; kc++) {
            bf16x8 b = w1v[(nt * 4 + kc) * 64 + lane];
            c = __builtin_amdgcn_mfma_f32_16x16x32_bf16(a[kc], b, c, 0, 0, 0);
        }
        int colc = nt * 16 + mrow;
        float bb = bias[colc];
#pragma unroll
        for (int i2 = 0; i2 < 4; i2++) {
            float v = fmaxf(c[i2] + bb, 0.f) * dv[i2];
            Hl[(quad * 4 + i2) * LDSTRIDE + colc] = f2bf(v);
        }
    }
    __syncthreads();

    // ---- GEMM2: nt range split by wave ----
    bf16x8 hh[8];
    const unsigned short* hrow = Hl + mrow * LDSTRIDE + quad * 8;
#pragma unroll
    for (int kc = 0; kc < 8; kc++) hh[kc] = *(const bf16x8*)(hrow + kc * 32);
    const bf16x8* w2v = (const bf16x8*)W2s;
    for (int nt = wave * 4; nt < wave * 4 + 4; nt++) {
        f32x4 c = {0.f, 0.f, 0.f, 0.f};
#pragma unroll
        for (int kc = 0; kc < 8; kc++) {
            bf16x8 b = w2v[(nt * 8 + kc) * 64 + lane];
            c = __builtin_amdgcn_mfma_f32_16x16x32_bf16(hh[kc], b, c, 0, 0, 0);
        }
        int colc = nt * 16 + mrow;
#pragma unroll
        for (int i2 = 0; i2 < 4; i2++) {
            int gr = m0 + quad * 4 + i2;
            if (gr < M) T[(size_t)gr * 128 + colc] = f2bf(c[i2]);
        }
    }
}

extern "C" void kernel_launch(void* const* d_in, const int* in_sizes, int n_in,
                              void* d_out, int out_size, void* d_ws, size_t ws_size,
                              hipStream_t stream) {
    const float* x  = (const float*)d_in[0];
    const int* ei   = (const int*)d_in[1];     // int32 (JAX x64 disabled)
    const float* W1 = (const float*)d_in[2];
    const float* b1 = (const float*)d_in[3];
    const float* W2 = (const float*)d_in[4];
    const float* b2 = (const float*)d_in[5];
    float* out      = (float*)d_out;

    const int N = in_sizes[0] / 128;
    const int E = in_sizes[1] / 2;
    const int* src = ei;
    const int* dst = ei + E;

    const int nbuck = (N + BMASK) >> BSHIFT;                // 391
    const int cap = E / nbuck + E / (4 * nbuck) + 512;      // ~3069

    // Workspace: dinv | Ts | Xs | W1s | W2s | rowbeg | rowend | ctrl | bbuf | col
    float* ws = (float*)d_ws;
    size_t Np = ((size_t)N + 255) & ~(size_t)255;
    float*          dinv = ws;
    unsigned short* Ts   = (unsigned short*)(dinv + Np);    // N*128 bf16
    unsigned short* Xs   = Ts + (size_t)N * 128;            // N*128 bf16
    unsigned short* W1s  = Xs + (size_t)N * 128;            // 32768
    unsigned short* W2s  = W1s + 32768;                     // 32768
    int* rowbeg = (int*)(W2s + 32768);                      // N
    int* rowend = rowbeg + Np;                              // N
    int* ctrl   = rowend + Np;                              // bcur[512]
    int* bcur   = ctrl;
    unsigned int* bbuf = (unsigned int*)(ctrl + 512);       // nbuck*cap packed
    int* col    = (int*)(bbuf + (size_t)nbuck * cap);       // nbuck*cap

    // 1. weight swizzle + ctrl zero, then CSR build
    wswz_kernel<<<256, 256, 0, stream>>>(W1, W2, W1s, W2s, ctrl);
    int nbins = (E + 2047) / 2048;                          // 391
    bin_kernel<<<nbins, 256, 0, stream>>>(src, dst, bcur, bbuf, E, cap, nbuck);
    bucket_csr_kernel<<<nbuck, 256, 0, stream>>>(bcur, bbuf, x, col, rowbeg, rowend,
                                                 dinv, Xs, N, cap);

    // 2. fused gather1 + GEMM1 + GEMM2 -> Ts (2 waves per 16-row tile)
    int mtiles = (N + 15) / 16;
    gemm_fused_kernel<<<mtiles, 128, 0, stream>>>(rowbeg, rowend, col, Xs,
                                                  W1s, W2s, b1, dinv, Ts, N);

    // 3. gather2 + fused bias/relu -> out
    int gth = N * 32;
    gather2_kernel<<<(gth + 255) / 256, 256, 0, stream>>>(rowbeg, rowend, col, Ts,
                                                          dinv, b2, out, N);
}

// Round 4
// 199.441 us; speedup vs baseline: 1.0775x; 1.0775x over previous
//
#include <hip/hip_runtime.h>

// GCN 2-layer, R17 = R15 with gather1 restructured to the gather2 shape:
// half-wave (32 lanes) per row, 8 B/lane ushort4 loads, 8-edge unroll ->
// 1 load-instr per edge (was 4), per-row imbalance (was max over 16 rows),
// 16-VGPR load window. Block=256 = 4 waves/tile; aggregated bf16 A-tile
// goes through 4.3 KB LDS; GEMM1 nt split 4/wave, GEMM2 2/wave.
// R16 lesson: hand ping-pong pipelines regress (compiler re-serializes,
// speculative col reads duplicate fetches: FETCH +17MB, dur +30%).
//   wswz(+ctrl zero) | bin | bucket_csr(dinv,Xs) | gemm_fused | gather2
// Lessons: no global atomic work queues (R7); no serial straggler blocks (R9);
// zero ALL control memory (R11); min-waves must fit live regs (R14); don't
// hand-pipeline scattered loads (R16) - restructure for fat per-instr rows.

typedef short bf16x8 __attribute__((ext_vector_type(8)));
typedef float f32x4 __attribute__((ext_vector_type(4)));

#define LDSTRIDE 264   // H tile: 16 rows * 264 ushort = 528 B/row, 16B-aligned
#define XTSTRIDE 136   // A tile: 16 rows * 136 ushort = 272 B/row, 16B-aligned
#define BSHIFT 7       // 128 dsts per bucket
#define BMASK 127

__device__ inline unsigned short f2bf(float f) {          // RNE
    unsigned int u = __float_as_uint(f);
    u += 0x7FFF + ((u >> 16) & 1);
    return (unsigned short)(u >> 16);
}
__device__ inline float bf2f(unsigned short h) {
    return __uint_as_float(((unsigned int)h) << 16);
}

// ---------- W swizzle into MFMA b-frag order + ctrl zero ----------
__device__ inline void swz1(const float* W, unsigned short* Ws, int K, int N, int i) {
    int k = i / N, n = i % N;
    int KC = K >> 5;
    size_t d = ((((size_t)(n >> 4) * KC + (k >> 5)) * 64) + ((k >> 3) & 3) * 16 + (n & 15)) * 8
               + (k & 7);
    Ws[d] = f2bf(W[i]);
}
__global__ void wswz_kernel(const float* __restrict__ W1, const float* __restrict__ W2,
                            unsigned short* __restrict__ W1s, unsigned short* __restrict__ W2s,
                            int* __restrict__ ctrl) {
    int i = blockIdx.x * blockDim.x + threadIdx.x;
    if (blockIdx.x == 0) {                     // zero ALL 512 ctrl ints
        for (int j = threadIdx.x; j < 512; j += 256) ctrl[j] = 0;
    }
    if (i < 32768) swz1(W1, W1s, 128, 256, i);
    else if (i < 65536) swz1(W2, W2s, 256, 128, i - 32768);
}

// ---------- pass 1: bin edges by dst>>7 (4 B packed) ----------
__global__ __launch_bounds__(256) void bin_kernel(
    const int* __restrict__ src, const int* __restrict__ dst,
    int* __restrict__ bcur, unsigned int* __restrict__ bbuf,
    int E, int cap, int nbuck) {
    __shared__ int cnt[512];
    __shared__ int base[512];
    int t = threadIdx.x;
    for (int i = t; i < nbuck; i += 256) cnt[i] = 0;
    __syncthreads();
    int e0 = blockIdx.x * 2048;
    unsigned int p_[8];
    int b_[8];
#pragma unroll
    for (int i = 0; i < 8; i++) {
        int e = e0 + i * 256 + t;
        if (e < E) {
            int s = src[e], d = dst[e];
            b_[i] = d >> BSHIFT;
            p_[i] = ((unsigned)(d & BMASK) << 24) | (unsigned)s;   // N < 2^24
            atomicAdd(&cnt[b_[i]], 1);
        } else b_[i] = -1;
    }
    __syncthreads();
    for (int b = t; b < nbuck; b += 256) {
        int c = cnt[b];
        base[b] = (c > 0) ? atomicAdd(&bcur[b], c) : 0;
    }
    __syncthreads();
    for (int i = t; i < nbuck; i += 256) cnt[i] = 0;   // reuse as cursor
    __syncthreads();
#pragma unroll
    for (int i = 0; i < 8; i++) {
        if (b_[i] >= 0) {
            int b = b_[i];
            int p = base[b] + atomicAdd(&cnt[b], 1);
            if (p >= 0 && p < cap) bbuf[(size_t)b * cap + p] = p_[i];
        }
    }
}

// ---------- pass 2: per-bucket (128 dsts) CSR + dinv + fused Xs ----------
__global__ __launch_bounds__(256) void bucket_csr_kernel(
    const int* __restrict__ bcur, const unsigned int* __restrict__ bbuf,
    const float* __restrict__ x,
    int* __restrict__ col, int* __restrict__ rowbeg, int* __restrict__ rowend,
    float* __restrict__ dinv, unsigned short* __restrict__ Xs, int N, int cap) {
    __shared__ int ldeg[128];
    __shared__ int lrp[256];
    __shared__ float sdv[128];
    int b = blockIdx.x, t = threadIdx.x;
    int cnt = min(max(bcur[b], 0), cap);
    if (t < 128) ldeg[t] = 0;
    __syncthreads();
    const unsigned int* mybuf = bbuf + (size_t)b * cap;
    for (int i = t; i < cnt; i += 256)
        atomicAdd(&ldeg[mybuf[i] >> 24], 1);
    __syncthreads();
    int v = (t < 128) ? ldeg[t] : 0;
    lrp[t] = v;
    __syncthreads();
    for (int off = 1; off < 128; off <<= 1) {    // inclusive scan (128 live)
        int u = (t >= off) ? lrp[t - off] : 0;
        __syncthreads();
        lrp[t] += u;
        __syncthreads();
    }
    int excl = lrp[t] - v;
    int gbase = b * cap;
    if (t < 128) {
        int r = b * 128 + t;
        float dv = rsqrtf((float)v + 1.0f);      // self-loop adds 1
        sdv[t] = dv;
        if (r < N) {
            rowbeg[r] = gbase + excl;
            rowend[r] = gbase + excl + v;
            dinv[r] = dv;
        }
        ldeg[t] = excl;    // reuse as cursor
    }
    __syncthreads();
    for (int i = t; i < cnt; i += 256) {
        unsigned int pr = mybuf[i];
        int p = atomicAdd(&ldeg[pr >> 24], 1);
        col[gbase + p] = (int)(pr & 0xffffffu);
    }
    // fused Xs: rows b*128..+127, coalesced ushort4
    int rbase = b * 128;
    for (int i = t; i < 128 * 32; i += 256) {
        int rl = i >> 5;
        int gr = rbase + rl;
        if (gr >= N) break;
        float s = sdv[rl];
        float4 xv = ((const float4*)x)[(size_t)gr * 32 + (i & 31)];
        ushort4 o;
        o.x = f2bf(xv.x * s); o.y = f2bf(xv.y * s);
        o.z = f2bf(xv.z * s); o.w = f2bf(xv.w * s);
        ((ushort4*)Xs)[(size_t)gr * 32 + (i & 31)] = o;
    }
}

// ---------- gather2: half-wave per row, ushort4/lane, unroll x8, fused epi ----------
__global__ __launch_bounds__(256) void gather2_kernel(
    const int* __restrict__ rowbeg, const int* __restrict__ rowend,
    const int* __restrict__ col, const unsigned short* __restrict__ P,
    const float* __restrict__ dinv, const float* __restrict__ bias,
    float* __restrict__ OF, int N) {
    int gid = blockIdx.x * blockDim.x + threadIdx.x;
    int r = gid >> 5;
    if (r >= N) return;
    int lane = gid & 31;
    const size_t off = (size_t)lane * 4;
    const unsigned short* Pf = P + off;

    ushort4 u = *(const ushort4*)(Pf + (size_t)r * 128);
    float ax = bf2f(u.x), ay = bf2f(u.y), az = bf2f(u.z), aw = bf2f(u.w);

    int beg = rowbeg[r], end = rowend[r];
    int i = beg;
    for (; i + 7 < end; i += 8) {
        ushort4 v0 = *(const ushort4*)(Pf + (size_t)col[i + 0] * 128);
        ushort4 v1 = *(const ushort4*)(Pf + (size_t)col[i + 1] * 128);
        ushort4 v2 = *(const ushort4*)(Pf + (size_t)col[i + 2] * 128);
        ushort4 v3 = *(const ushort4*)(Pf + (size_t)col[i + 3] * 128);
        ushort4 v4 = *(const ushort4*)(Pf + (size_t)col[i + 4] * 128);
        ushort4 v5 = *(const ushort4*)(Pf + (size_t)col[i + 5] * 128);
        ushort4 v6 = *(const ushort4*)(Pf + (size_t)col[i + 6] * 128);
        ushort4 v7 = *(const ushort4*)(Pf + (size_t)col[i + 7] * 128);
        ax += bf2f(v0.x) + bf2f(v1.x) + bf2f(v2.x) + bf2f(v3.x)
            + bf2f(v4.x) + bf2f(v5.x) + bf2f(v6.x) + bf2f(v7.x);
        ay += bf2f(v0.y) + bf2f(v1.y) + bf2f(v2.y) + bf2f(v3.y)
            + bf2f(v4.y) + bf2f(v5.y) + bf2f(v6.y) + bf2f(v7.y);
        az += bf2f(v0.z) + bf2f(v1.z) + bf2f(v2.z) + bf2f(v3.z)
            + bf2f(v4.z) + bf2f(v5.z) + bf2f(v6.z) + bf2f(v7.z);
        aw += bf2f(v0.w) + bf2f(v1.w) + bf2f(v2.w) + bf2f(v3.w)
            + bf2f(v4.w) + bf2f(v5.w) + bf2f(v6.w) + bf2f(v7.w);
    }
    for (; i < end; i++) {
        ushort4 a = *(const ushort4*)(Pf + (size_t)col[i] * 128);
        ax += bf2f(a.x); ay += bf2f(a.y); az += bf2f(a.z); aw += bf2f(a.w);
    }
    float s = dinv[r];
    float4 bb = *(const float4*)(bias + off);
    float4 o;
    o.x = fmaxf(ax * s + bb.x, 0.f);
    o.y = fmaxf(ay * s + bb.y, 0.f);
    o.z = fmaxf(az * s + bb.z, 0.f);
    o.w = fmaxf(aw * s + bb.w, 0.f);
    *(float4*)(OF + (size_t)r * 128 + off) = o;
}

// ---------- fused gather1 + GEMM1 + GEMM2, gather2-shaped aggregation ----------
// Block = 256 thr (4 waves, 8 half-waves) per 16-row tile. Each half-wave
// aggregates 2 rows (lane owns 4 features, ushort4 loads, 8-edge unroll),
// scales by dinv, writes bf16 row to Xt LDS. Barrier. All 4 waves read MFMA
// a-frags from Xt; GEMM1 splits 16 nt 4/wave -> Ht LDS; GEMM2 splits 8 nt
// 2/wave -> T. Per-edge cost: ONE 256-B row per half-wave load instruction.
__global__ __launch_bounds__(256, 4) void gemm_fused_kernel(
    const int* __restrict__ rowbeg, const int* __restrict__ rowend,
    const int* __restrict__ col, const unsigned short* __restrict__ Xs,
    const unsigned short* __restrict__ W1s, const unsigned short* __restrict__ W2s,
    const float* __restrict__ bias, const float* __restrict__ dinv,
    unsigned short* __restrict__ T, int M) {
    __shared__ unsigned short Xt[16 * XTSTRIDE];   // 4352 B: aggregated bf16 A tile
    __shared__ unsigned short Ht[16 * LDSTRIDE];   // 8448 B: H tile

    int t = threadIdx.x;
    int m0 = blockIdx.x * 16;
    int hw = t >> 5;            // half-wave 0..7
    int l  = t & 31;
    const unsigned short* Pf = Xs + (size_t)l * 4;

#pragma unroll
    for (int sub = 0; sub < 2; sub++) {
        int lr = hw * 2 + sub;                 // local row 0..15
        int r = m0 + lr;
        int rc = (r < M) ? r : (M - 1);
        ushort4 u = *(const ushort4*)(Pf + (size_t)rc * 128);   // self-loop
        float ax = bf2f(u.x), ay = bf2f(u.y), az = bf2f(u.z), aw = bf2f(u.w);
        int beg = rowbeg[rc], end = rowend[rc];
        int i = beg;
        for (; i + 7 < end; i += 8) {
            ushort4 v0 = *(const ushort4*)(Pf + (size_t)col[i + 0] * 128);
            ushort4 v1 = *(const ushort4*)(Pf + (size_t)col[i + 1] * 128);
            ushort4 v2 = *(const ushort4*)(Pf + (size_t)col[i + 2] * 128);
            ushort4 v3 = *(const ushort4*)(Pf + (size_t)col[i + 3] * 128);
            ushort4 v4 = *(const ushort4*)(Pf + (size_t)col[i + 4] * 128);
            ushort4 v5 = *(const ushort4*)(Pf + (size_t)col[i + 5] * 128);
            ushort4 v6 = *(const ushort4*)(Pf + (size_t)col[i + 6] * 128);
            ushort4 v7 = *(const ushort4*)(Pf + (size_t)col[i + 7] * 128);
            ax += bf2f(v0.x) + bf2f(v1.x) + bf2f(v2.x) + bf2f(v3.x)
                + bf2f(v4.x) + bf2f(v5.x) + bf2f(v6.x) + bf2f(v7.x);
            ay += bf2f(v0.y) + bf2f(v1.y) + bf2f(v2.y) + bf2f(v3.y)
                + bf2f(v4.y) + bf2f(v5.y) + bf2f(v6.y) + bf2f(v7.y);
            az += bf2f(v0.z) + bf2f(v1.z) + bf2f(v2.z) + bf2f(v3.z)
                + bf2f(v4.z) + bf2f(v5.z) + bf2f(v6.z) + bf2f(v7.z);
            aw += bf2f(v0.w) + bf2f(v1.w) + bf2f(v2.w) + bf2f(v3.w)
                + bf2f(v4.w) + bf2f(v5.w) + bf2f(v6.w) + bf2f(v7.w);
        }
        for (; i < end; i++) {
            ushort4 a = *(const ushort4*)(Pf + (size_t)col[i] * 128);
            ax += bf2f(a.x); ay += bf2f(a.y); az += bf2f(a.z); aw += bf2f(a.w);
        }
        float dvr = dinv[rc];
        ushort4 o;
        o.x = f2bf(ax * dvr); o.y = f2bf(ay * dvr);
        o.z = f2bf(az * dvr); o.w = f2bf(aw * dvr);
        *(ushort4*)(Xt + lr * XTSTRIDE + l * 4) = o;
    }
    __syncthreads();

    int wave = t >> 6;
    int lane = t & 63;
    int mrow = lane & 15, quad = lane >> 4;

    bf16x8 a[4];
#pragma unroll
    for (int kc = 0; kc < 4; kc++)
        a[kc] = *(const bf16x8*)(Xt + mrow * XTSTRIDE + kc * 32 + quad * 8);

    float dv[4];
#pragma unroll
    for (int i2 = 0; i2 < 4; i2++) {
        int gr = m0 + quad * 4 + i2;
        dv[i2] = dinv[gr < M ? gr : M - 1];
    }

    // ---- GEMM1: 16 nt tiles split 4 per wave -> Ht ----
    const bf16x8* w1v = (const bf16x8*)W1s;
    for (int nt = wave * 4; nt < wave * 4 + 4; nt++) {
        f32x4 c = {0.f, 0.f, 0.f, 0.f};
#pragma unroll
        for (int kc = 0; kc < 4; kc++) {
            bf16x8 b = w1v[(nt * 4 + kc) * 64 + lane];
            c = __builtin_amdgcn_mfma_f32_16x16x32_bf16(a[kc], b, c, 0, 0, 0);
        }
        int colc = nt * 16 + mrow;
        float bb = bias[colc];
#pragma unroll
        for (int i2 = 0; i2 < 4; i2++) {
            float v = fmaxf(c[i2] + bb, 0.f) * dv[i2];
            Ht[(quad * 4 + i2) * LDSTRIDE + colc] = f2bf(v);
        }
    }
    __syncthreads();

    // ---- GEMM2: 8 nt tiles split 2 per wave -> T ----
    bf16x8 hh[8];
    const unsigned short* hrow = Ht + mrow * LDSTRIDE + quad * 8;
#pragma unroll
    for (int kc = 0; kc < 8; kc++) hh[kc] = *(const bf16x8*)(hrow + kc * 32);
    const bf16x8* w2v = (const bf16x8*)W2s;
    for (int nt = wave * 2; nt < wave * 2 + 2; nt++) {
        f32x4 c = {0.f, 0.f, 0.f, 0.f};
#pragma unroll
        for (int kc = 0; kc < 8; kc++) {
            bf16x8 b = w2v[(nt * 8 + kc) * 64 + lane];
            c = __builtin_amdgcn_mfma_f32_16x16x32_bf16(hh[kc], b, c, 0, 0, 0);
        }
        int colc = nt * 16 + mrow;
#pragma unroll
        for (int i2 = 0; i2 < 4; i2++) {
            int gr = m0 + quad * 4 + i2;
            if (gr < M) T[(size_t)gr * 128 + colc] = f2bf(c[i2]);
        }
    }
}

extern "C" void kernel_launch(void* const* d_in, const int* in_sizes, int n_in,
                              void* d_out, int out_size, void* d_ws, size_t ws_size,
                              hipStream_t stream) {
    const float* x  = (const float*)d_in[0];
    const int* ei   = (const int*)d_in[1];     // int32 (JAX x64 disabled)
    const float* W1 = (const float*)d_in[2];
    const float* b1 = (const float*)d_in[3];
    const float* W2 = (const float*)d_in[4];
    const float* b2 = (const float*)d_in[5];
    float* out      = (float*)d_out;

    const int N = in_sizes[0] / 128;
    const int E = in_sizes[1] / 2;
    const int* src = ei;
    const int* dst = ei + E;

    const int nbuck = (N + BMASK) >> BSHIFT;                // 391
    const int cap = E / nbuck + E / (4 * nbuck) + 512;      // ~3069

    // Workspace: dinv | Ts | Xs | W1s | W2s | rowbeg | rowend | ctrl | bbuf | col
    float* ws = (float*)d_ws;
    size_t Np = ((size_t)N + 255) & ~(size_t)255;
    float*          dinv = ws;
    unsigned short* Ts   = (unsigned short*)(dinv + Np);    // N*128 bf16
    unsigned short* Xs   = Ts + (size_t)N * 128;            // N*128 bf16
    unsigned short* W1s  = Xs + (size_t)N * 128;            // 32768
    unsigned short* W2s  = W1s + 32768;                     // 32768
    int* rowbeg = (int*)(W2s + 32768);                      // N
    int* rowend = rowbeg + Np;                              // N
    int* ctrl   = rowend + Np;                              // bcur[512]
    int* bcur   = ctrl;
    unsigned int* bbuf = (unsigned int*)(ctrl + 512);       // nbuck*cap packed
    int* col    = (int*)(bbuf + (size_t)nbuck * cap);       // nbuck*cap

    // 1. weight swizzle + ctrl zero, then CSR build
    wswz_kernel<<<256, 256, 0, stream>>>(W1, W2, W1s, W2s, ctrl);
    int nbins = (E + 2047) / 2048;                          // 391
    bin_kernel<<<nbins, 256, 0, stream>>>(src, dst, bcur, bbuf, E, cap, nbuck);
    bucket_csr_kernel<<<nbuck, 256, 0, stream>>>(bcur, bbuf, x, col, rowbeg, rowend,
                                                 dinv, Xs, N, cap);

    // 2. fused gather1 + GEMM1 + GEMM2 -> Ts (4 waves per 16-row tile)
    int mtiles = (N + 15) / 16;
    gemm_fused_kernel<<<mtiles, 256, 0, stream>>>(rowbeg, rowend, col, Xs,
                                                  W1s, W2s, b1, dinv, Ts, N);

    // 3. gather2 + fused bias/relu -> out
    int gth = N * 32;
    gather2_kernel<<<(gth + 255) / 256, 256, 0, stream>>>(rowbeg, rowend, col, Ts,
                                                          dinv, b2, out, N);
}

// Round 5
// 192.744 us; speedup vs baseline: 1.1150x; 1.0347x over previous
//
#include <hip/hip_runtime.h>

// GCN 2-layer, R18 = R17 + (a) one half-wave per row in gather1 (block=512,
// 16 half-waves per 16-row tile; kills the serial 2-row sub-loop), (b) masked
// 8-batch tail in BOTH gathers (clamped idx + 0/1 selector fma) - no serial
// dependent-load tail. R17 evidence: 37 CU-cy/edge vs ~11 floor; serial tail
// (~3.5 edges x 600cy) + 2-row serialization explain the gap.
//   wswz(+ctrl zero) | bin | bucket_csr(dinv,Xs) | gemm_fused | gather2
// Lessons: no global atomic work queues (R7); no serial straggler blocks (R9);
// zero ALL control memory (R11); min-waves must fit live regs (R14); don't
// hand-pipeline scattered loads (R16) - restructure for fat per-instr rows
// (R17); never leave a serial dependent-load tail loop (R18).

typedef short bf16x8 __attribute__((ext_vector_type(8)));
typedef float f32x4 __attribute__((ext_vector_type(4)));

#define LDSTRIDE 264   // H tile: 16 rows * 264 ushort = 528 B/row, 16B-aligned
#define XTSTRIDE 136   // A tile: 16 rows * 136 ushort = 272 B/row, 16B-aligned
#define BSHIFT 7       // 128 dsts per bucket
#define BMASK 127

__device__ inline unsigned short f2bf(float f) {          // RNE
    unsigned int u = __float_as_uint(f);
    u += 0x7FFF + ((u >> 16) & 1);
    return (unsigned short)(u >> 16);
}
__device__ inline float bf2f(unsigned short h) {
    return __uint_as_float(((unsigned int)h) << 16);
}

// ---------- W swizzle into MFMA b-frag order + ctrl zero ----------
__device__ inline void swz1(const float* W, unsigned short* Ws, int K, int N, int i) {
    int k = i / N, n = i % N;
    int KC = K >> 5;
    size_t d = ((((size_t)(n >> 4) * KC + (k >> 5)) * 64) + ((k >> 3) & 3) * 16 + (n & 15)) * 8
               + (k & 7);
    Ws[d] = f2bf(W[i]);
}
__global__ void wswz_kernel(const float* __restrict__ W1, const float* __restrict__ W2,
                            unsigned short* __restrict__ W1s, unsigned short* __restrict__ W2s,
                            int* __restrict__ ctrl) {
    int i = blockIdx.x * blockDim.x + threadIdx.x;
    if (blockIdx.x == 0) {                     // zero ALL 512 ctrl ints
        for (int j = threadIdx.x; j < 512; j += 256) ctrl[j] = 0;
    }
    if (i < 32768) swz1(W1, W1s, 128, 256, i);
    else if (i < 65536) swz1(W2, W2s, 256, 128, i - 32768);
}

// ---------- pass 1: bin edges by dst>>7 (4 B packed) ----------
__global__ __launch_bounds__(256) void bin_kernel(
    const int* __restrict__ src, const int* __restrict__ dst,
    int* __restrict__ bcur, unsigned int* __restrict__ bbuf,
    int E, int cap, int nbuck) {
    __shared__ int cnt[512];
    __shared__ int base[512];
    int t = threadIdx.x;
    for (int i = t; i < nbuck; i += 256) cnt[i] = 0;
    __syncthreads();
    int e0 = blockIdx.x * 2048;
    unsigned int p_[8];
    int b_[8];
#pragma unroll
    for (int i = 0; i < 8; i++) {
        int e = e0 + i * 256 + t;
        if (e < E) {
            int s = src[e], d = dst[e];
            b_[i] = d >> BSHIFT;
            p_[i] = ((unsigned)(d & BMASK) << 24) | (unsigned)s;   // N < 2^24
            atomicAdd(&cnt[b_[i]], 1);
        } else b_[i] = -1;
    }
    __syncthreads();
    for (int b = t; b < nbuck; b += 256) {
        int c = cnt[b];
        base[b] = (c > 0) ? atomicAdd(&bcur[b], c) : 0;
    }
    __syncthreads();
    for (int i = t; i < nbuck; i += 256) cnt[i] = 0;   // reuse as cursor
    __syncthreads();
#pragma unroll
    for (int i = 0; i < 8; i++) {
        if (b_[i] >= 0) {
            int b = b_[i];
            int p = base[b] + atomicAdd(&cnt[b], 1);
            if (p >= 0 && p < cap) bbuf[(size_t)b * cap + p] = p_[i];
        }
    }
}

// ---------- pass 2: per-bucket (128 dsts) CSR + dinv + fused Xs ----------
__global__ __launch_bounds__(256) void bucket_csr_kernel(
    const int* __restrict__ bcur, const unsigned int* __restrict__ bbuf,
    const float* __restrict__ x,
    int* __restrict__ col, int* __restrict__ rowbeg, int* __restrict__ rowend,
    float* __restrict__ dinv, unsigned short* __restrict__ Xs, int N, int cap) {
    __shared__ int ldeg[128];
    __shared__ int lrp[256];
    __shared__ float sdv[128];
    int b = blockIdx.x, t = threadIdx.x;
    int cnt = min(max(bcur[b], 0), cap);
    if (t < 128) ldeg[t] = 0;
    __syncthreads();
    const unsigned int* mybuf = bbuf + (size_t)b * cap;
    for (int i = t; i < cnt; i += 256)
        atomicAdd(&ldeg[mybuf[i] >> 24], 1);
    __syncthreads();
    int v = (t < 128) ? ldeg[t] : 0;
    lrp[t] = v;
    __syncthreads();
    for (int off = 1; off < 128; off <<= 1) {    // inclusive scan (128 live)
        int u = (t >= off) ? lrp[t - off] : 0;
        __syncthreads();
        lrp[t] += u;
        __syncthreads();
    }
    int excl = lrp[t] - v;
    int gbase = b * cap;
    if (t < 128) {
        int r = b * 128 + t;
        float dv = rsqrtf((float)v + 1.0f);      // self-loop adds 1
        sdv[t] = dv;
        if (r < N) {
            rowbeg[r] = gbase + excl;
            rowend[r] = gbase + excl + v;
            dinv[r] = dv;
        }
        ldeg[t] = excl;    // reuse as cursor
    }
    __syncthreads();
    for (int i = t; i < cnt; i += 256) {
        unsigned int pr = mybuf[i];
        int p = atomicAdd(&ldeg[pr >> 24], 1);
        col[gbase + p] = (int)(pr & 0xffffffu);
    }
    // fused Xs: rows b*128..+127, coalesced ushort4
    int rbase = b * 128;
    for (int i = t; i < 128 * 32; i += 256) {
        int rl = i >> 5;
        int gr = rbase + rl;
        if (gr >= N) break;
        float s = sdv[rl];
        float4 xv = ((const float4*)x)[(size_t)gr * 32 + (i & 31)];
        ushort4 o;
        o.x = f2bf(xv.x * s); o.y = f2bf(xv.y * s);
        o.z = f2bf(xv.z * s); o.w = f2bf(xv.w * s);
        ((ushort4*)Xs)[(size_t)gr * 32 + (i & 31)] = o;
    }
}

// ---------- gather2: half-wave per row, ushort4/lane, masked-batch tail ----------
__global__ __launch_bounds__(256) void gather2_kernel(
    const int* __restrict__ rowbeg, const int* __restrict__ rowend,
    const int* __restrict__ col, const unsigned short* __restrict__ P,
    const float* __restrict__ dinv, const float* __restrict__ bias,
    float* __restrict__ OF, int N) {
    int gid = blockIdx.x * blockDim.x + threadIdx.x;
    int r = gid >> 5;
    if (r >= N) return;
    int lane = gid & 31;
    const size_t off = (size_t)lane * 4;
    const unsigned short* Pf = P + off;

    ushort4 u = *(const ushort4*)(Pf + (size_t)r * 128);
    float ax = bf2f(u.x), ay = bf2f(u.y), az = bf2f(u.z), aw = bf2f(u.w);

    int beg = rowbeg[r], end = rowend[r];
    int i = beg;
    for (; i + 7 < end; i += 8) {
        ushort4 v0 = *(const ushort4*)(Pf + (size_t)col[i + 0] * 128);
        ushort4 v1 = *(const ushort4*)(Pf + (size_t)col[i + 1] * 128);
        ushort4 v2 = *(const ushort4*)(Pf + (size_t)col[i + 2] * 128);
        ushort4 v3 = *(const ushort4*)(Pf + (size_t)col[i + 3] * 128);
        ushort4 v4 = *(const ushort4*)(Pf + (size_t)col[i + 4] * 128);
        ushort4 v5 = *(const ushort4*)(Pf + (size_t)col[i + 5] * 128);
        ushort4 v6 = *(const ushort4*)(Pf + (size_t)col[i + 6] * 128);
        ushort4 v7 = *(const ushort4*)(Pf + (size_t)col[i + 7] * 128);
        ax += bf2f(v0.x) + bf2f(v1.x) + bf2f(v2.x) + bf2f(v3.x)
            + bf2f(v4.x) + bf2f(v5.x) + bf2f(v6.x) + bf2f(v7.x);
        ay += bf2f(v0.y) + bf2f(v1.y) + bf2f(v2.y) + bf2f(v3.y)
            + bf2f(v4.y) + bf2f(v5.y) + bf2f(v6.y) + bf2f(v7.y);
        az += bf2f(v0.z) + bf2f(v1.z) + bf2f(v2.z) + bf2f(v3.z)
            + bf2f(v4.z) + bf2f(v5.z) + bf2f(v6.z) + bf2f(v7.z);
        aw += bf2f(v0.w) + bf2f(v1.w) + bf2f(v2.w) + bf2f(v3.w)
            + bf2f(v4.w) + bf2f(v5.w) + bf2f(v6.w) + bf2f(v7.w);
    }
    if (i < end) {                               // ONE masked batch, no serial tail
        int cl = end - 1;
        int e1 = i + 1 < end ? i + 1 : cl, e2 = i + 2 < end ? i + 2 : cl;
        int e3 = i + 3 < end ? i + 3 : cl, e4 = i + 4 < end ? i + 4 : cl;
        int e5 = i + 5 < end ? i + 5 : cl, e6 = i + 6 < end ? i + 6 : cl;
        int e7 = i + 7 < end ? i + 7 : cl;
        float m1 = i + 1 < end ? 1.f : 0.f, m2 = i + 2 < end ? 1.f : 0.f;
        float m3 = i + 3 < end ? 1.f : 0.f, m4 = i + 4 < end ? 1.f : 0.f;
        float m5 = i + 5 < end ? 1.f : 0.f, m6 = i + 6 < end ? 1.f : 0.f;
        float m7 = i + 7 < end ? 1.f : 0.f;
        ushort4 v0 = *(const ushort4*)(Pf + (size_t)col[i] * 128);
        ushort4 v1 = *(const ushort4*)(Pf + (size_t)col[e1] * 128);
        ushort4 v2 = *(const ushort4*)(Pf + (size_t)col[e2] * 128);
        ushort4 v3 = *(const ushort4*)(Pf + (size_t)col[e3] * 128);
        ushort4 v4 = *(const ushort4*)(Pf + (size_t)col[e4] * 128);
        ushort4 v5 = *(const ushort4*)(Pf + (size_t)col[e5] * 128);
        ushort4 v6 = *(const ushort4*)(Pf + (size_t)col[e6] * 128);
        ushort4 v7 = *(const ushort4*)(Pf + (size_t)col[e7] * 128);
        ax += bf2f(v0.x) + m1 * bf2f(v1.x) + m2 * bf2f(v2.x) + m3 * bf2f(v3.x)
            + m4 * bf2f(v4.x) + m5 * bf2f(v5.x) + m6 * bf2f(v6.x) + m7 * bf2f(v7.x);
        ay += bf2f(v0.y) + m1 * bf2f(v1.y) + m2 * bf2f(v2.y) + m3 * bf2f(v3.y)
            + m4 * bf2f(v4.y) + m5 * bf2f(v5.y) + m6 * bf2f(v6.y) + m7 * bf2f(v7.y);
        az += bf2f(v0.z) + m1 * bf2f(v1.z) + m2 * bf2f(v2.z) + m3 * bf2f(v3.z)
            + m4 * bf2f(v4.z) + m5 * bf2f(v5.z) + m6 * bf2f(v6.z) + m7 * bf2f(v7.z);
        aw += bf2f(v0.w) + m1 * bf2f(v1.w) + m2 * bf2f(v2.w) + m3 * bf2f(v3.w)
            + m4 * bf2f(v4.w) + m5 * bf2f(v5.w) + m6 * bf2f(v6.w) + m7 * bf2f(v7.w);
    }
    float s = dinv[r];
    float4 bb = *(const float4*)(bias + off);
    float4 o;
    o.x = fmaxf(ax * s + bb.x, 0.f);
    o.y = fmaxf(ay * s + bb.y, 0.f);
    o.z = fmaxf(az * s + bb.z, 0.f);
    o.w = fmaxf(aw * s + bb.w, 0.f);
    *(float4*)(OF + (size_t)r * 128 + off) = o;
}

// ---------- fused gather1 + GEMM1 + GEMM2, 1 half-wave per row ----------
// Block = 512 thr (8 waves, 16 half-waves) per 16-row tile: half-wave hw owns
// row m0+hw (lane owns 4 features, ushort4 loads, 8-edge unroll + masked-batch
// tail), scales by dinv, writes bf16 row to Xt. Barrier. 8 waves split GEMM1
// (2 nt/wave) -> Ht, GEMM2 (1 nt/wave) -> T. Thread-cap 4 blocks/CU = 32
// waves if VGPR <= 64 (R17 measured 36).
__global__ __launch_bounds__(512, 4) void gemm_fused_kernel(
    const int* __restrict__ rowbeg, const int* __restrict__ rowend,
    const int* __restrict__ col, const unsigned short* __restrict__ Xs,
    const unsigned short* __restrict__ W1s, const unsigned short* __restrict__ W2s,
    const float* __restrict__ bias, const float* __restrict__ dinv,
    unsigned short* __restrict__ T, int M) {
    __shared__ unsigned short Xt[16 * XTSTRIDE];   // 4352 B: aggregated bf16 A tile
    __shared__ unsigned short Ht[16 * LDSTRIDE];   // 8448 B: H tile

    int t = threadIdx.x;
    int m0 = blockIdx.x * 16;
    int hw = t >> 5;            // half-wave 0..15 = local row
    int l  = t & 31;
    const unsigned short* Pf = Xs + (size_t)l * 4;

    {
        int r = m0 + hw;
        int rc = (r < M) ? r : (M - 1);
        ushort4 u = *(const ushort4*)(Pf + (size_t)rc * 128);   // self-loop
        float ax = bf2f(u.x), ay = bf2f(u.y), az = bf2f(u.z), aw = bf2f(u.w);
        int beg = rowbeg[rc], end = rowend[rc];
        int i = beg;
        for (; i + 7 < end; i += 8) {
            ushort4 v0 = *(const ushort4*)(Pf + (size_t)col[i + 0] * 128);
            ushort4 v1 = *(const ushort4*)(Pf + (size_t)col[i + 1] * 128);
            ushort4 v2 = *(const ushort4*)(Pf + (size_t)col[i + 2] * 128);
            ushort4 v3 = *(const ushort4*)(Pf + (size_t)col[i + 3] * 128);
            ushort4 v4 = *(const ushort4*)(Pf + (size_t)col[i + 4] * 128);
            ushort4 v5 = *(const ushort4*)(Pf + (size_t)col[i + 5] * 128);
            ushort4 v6 = *(const ushort4*)(Pf + (size_t)col[i + 6] * 128);
            ushort4 v7 = *(const ushort4*)(Pf + (size_t)col[i + 7] * 128);
            ax += bf2f(v0.x) + bf2f(v1.x) + bf2f(v2.x) + bf2f(v3.x)
                + bf2f(v4.x) + bf2f(v5.x) + bf2f(v6.x) + bf2f(v7.x);
            ay += bf2f(v0.y) + bf2f(v1.y) + bf2f(v2.y) + bf2f(v3.y)
                + bf2f(v4.y) + bf2f(v5.y) + bf2f(v6.y) + bf2f(v7.y);
            az += bf2f(v0.z) + bf2f(v1.z) + bf2f(v2.z) + bf2f(v3.z)
                + bf2f(v4.z) + bf2f(v5.z) + bf2f(v6.z) + bf2f(v7.z);
            aw += bf2f(v0.w) + bf2f(v1.w) + bf2f(v2.w) + bf2f(v3.w)
                + bf2f(v4.w) + bf2f(v5.w) + bf2f(v6.w) + bf2f(v7.w);
        }
        if (i < end) {                           // ONE masked batch, no serial tail
            int cl = end - 1;
            int e1 = i + 1 < end ? i + 1 : cl, e2 = i + 2 < end ? i + 2 : cl;
            int e3 = i + 3 < end ? i + 3 : cl, e4 = i + 4 < end ? i + 4 : cl;
            int e5 = i + 5 < end ? i + 5 : cl, e6 = i + 6 < end ? i + 6 : cl;
            int e7 = i + 7 < end ? i + 7 : cl;
            float m1 = i + 1 < end ? 1.f : 0.f, m2 = i + 2 < end ? 1.f : 0.f;
            float m3 = i + 3 < end ? 1.f : 0.f, m4 = i + 4 < end ? 1.f : 0.f;
            float m5 = i + 5 < end ? 1.f : 0.f, m6 = i + 6 < end ? 1.f : 0.f;
            float m7 = i + 7 < end ? 1.f : 0.f;
            ushort4 v0 = *(const ushort4*)(Pf + (size_t)col[i] * 128);
            ushort4 v1 = *(const ushort4*)(Pf + (size_t)col[e1] * 128);
            ushort4 v2 = *(const ushort4*)(Pf + (size_t)col[e2] * 128);
            ushort4 v3 = *(const ushort4*)(Pf + (size_t)col[e3] * 128);
            ushort4 v4 = *(const ushort4*)(Pf + (size_t)col[e4] * 128);
            ushort4 v5 = *(const ushort4*)(Pf + (size_t)col[e5] * 128);
            ushort4 v6 = *(const ushort4*)(Pf + (size_t)col[e6] * 128);
            ushort4 v7 = *(const ushort4*)(Pf + (size_t)col[e7] * 128);
            ax += bf2f(v0.x) + m1 * bf2f(v1.x) + m2 * bf2f(v2.x) + m3 * bf2f(v3.x)
                + m4 * bf2f(v4.x) + m5 * bf2f(v5.x) + m6 * bf2f(v6.x) + m7 * bf2f(v7.x);
            ay += bf2f(v0.y) + m1 * bf2f(v1.y) + m2 * bf2f(v2.y) + m3 * bf2f(v3.y)
                + m4 * bf2f(v4.y) + m5 * bf2f(v5.y) + m6 * bf2f(v6.y) + m7 * bf2f(v7.y);
            az += bf2f(v0.z) + m1 * bf2f(v1.z) + m2 * bf2f(v2.z) + m3 * bf2f(v3.z)
                + m4 * bf2f(v4.z) + m5 * bf2f(v5.z) + m6 * bf2f(v6.z) + m7 * bf2f(v7.z);
            aw += bf2f(v0.w) + m1 * bf2f(v1.w) + m2 * bf2f(v2.w) + m3 * bf2f(v3.w)
                + m4 * bf2f(v4.w) + m5 * bf2f(v5.w) + m6 * bf2f(v6.w) + m7 * bf2f(v7.w);
        }
        float dvr = dinv[rc];
        ushort4 o;
        o.x = f2bf(ax * dvr); o.y = f2bf(ay * dvr);
        o.z = f2bf(az * dvr); o.w = f2bf(aw * dvr);
        *(ushort4*)(Xt + hw * XTSTRIDE + l * 4) = o;
    }
    __syncthreads();

    int wave = t >> 6;          // 0..7
    int lane = t & 63;
    int mrow = lane & 15, quad = lane >> 4;

    bf16x8 a[4];
#pragma unroll
    for (int kc = 0; kc < 4; kc++)
        a[kc] = *(const bf16x8*)(Xt + mrow * XTSTRIDE + kc * 32 + quad * 8);

    float dv[4];
#pragma unroll
    for (int i2 = 0; i2 < 4; i2++) {
        int gr = m0 + quad * 4 + i2;
        dv[i2] = dinv[gr < M ? gr : M - 1];
    }

    // ---- GEMM1: 16 nt tiles split 2 per wave -> Ht ----
    const bf16x8* w1v = (const bf16x8*)W1s;
    for (int nt = wave * 2; nt < wave * 2 + 2; nt++) {
        f32x4 c = {0.f, 0.f, 0.f, 0.f};
#pragma unroll
        for (int kc = 0; kc < 4; kc++) {
            bf16x8 b = w1v[(nt * 4 + kc) * 64 + lane];
            c = __builtin_amdgcn_mfma_f32_16x16x32_bf16(a[kc], b, c, 0, 0, 0);
        }
        int colc = nt * 16 + mrow;
        float bb = bias[colc];
#pragma unroll
        for (int i2 = 0; i2 < 4; i2++) {
            float v = fmaxf(c[i2] + bb, 0.f) * dv[i2];
            Ht[(quad * 4 + i2) * LDSTRIDE + colc] = f2bf(v);
        }
    }
    __syncthreads();

    // ---- GEMM2: 8 nt tiles, 1 per wave -> T ----
    bf16x8 hh[8];
    const unsigned short* hrow = Ht + mrow * LDSTRIDE + quad * 8;
#pragma unroll
    for (int kc = 0; kc < 8; kc++) hh[kc] = *(const bf16x8*)(hrow + kc * 32);
    const bf16x8* w2v = (const bf16x8*)W2s;
    {
        int nt = wave;
        f32x4 c = {0.f, 0.f, 0.f, 0.f};
#pragma unroll
        for (int kc = 0; kc < 8; kc++) {
            bf16x8 b = w2v[(nt * 8 + kc) * 64 + lane];
            c = __builtin_amdgcn_mfma_f32_16x16x32_bf16(hh[kc], b, c, 0, 0, 0);
        }
        int colc = nt * 16 + mrow;
#pragma unroll
        for (int i2 = 0; i2 < 4; i2++) {
            int gr = m0 + quad * 4 + i2;
            if (gr < M) T[(size_t)gr * 128 + colc] = f2bf(c[i2]);
        }
    }
}

extern "C" void kernel_launch(void* const* d_in, const int* in_sizes, int n_in,
                              void* d_out, int out_size, void* d_ws, size_t ws_size,
                              hipStream_t stream) {
    const float* x  = (const float*)d_in[0];
    const int* ei   = (const int*)d_in[1];     // int32 (JAX x64 disabled)
    const float* W1 = (const float*)d_in[2];
    const float* b1 = (const float*)d_in[3];
    const float* W2 = (const float*)d_in[4];
    const float* b2 = (const float*)d_in[5];
    float* out      = (float*)d_out;

    const int N = in_sizes[0] / 128;
    const int E = in_sizes[1] / 2;
    const int* src = ei;
    const int* dst = ei + E;

    const int nbuck = (N + BMASK) >> BSHIFT;                // 391
    const int cap = E / nbuck + E / (4 * nbuck) + 512;      // ~3069

    // Workspace: dinv | Ts | Xs | W1s | W2s | rowbeg | rowend | ctrl | bbuf | col
    float* ws = (float*)d_ws;
    size_t Np = ((size_t)N + 255) & ~(size_t)255;
    float*          dinv = ws;
    unsigned short* Ts   = (unsigned short*)(dinv + Np);    // N*128 bf16
    unsigned short* Xs   = Ts + (size_t)N * 128;            // N*128 bf16
    unsigned short* W1s  = Xs + (size_t)N * 128;            // 32768
    unsigned short* W2s  = W1s + 32768;                     // 32768
    int* rowbeg = (int*)(W2s + 32768);                      // N
    int* rowend = rowbeg + Np;                              // N
    int* ctrl   = rowend + Np;                              // bcur[512]
    int* bcur   = ctrl;
    unsigned int* bbuf = (unsigned int*)(ctrl + 512);       // nbuck*cap packed
    int* col    = (int*)(bbuf + (size_t)nbuck * cap);       // nbuck*cap

    // 1. weight swizzle + ctrl zero, then CSR build
    wswz_kernel<<<256, 256, 0, stream>>>(W1, W2, W1s, W2s, ctrl);
    int nbins = (E + 2047) / 2048;                          // 391
    bin_kernel<<<nbins, 256, 0, stream>>>(src, dst, bcur, bbuf, E, cap, nbuck);
    bucket_csr_kernel<<<nbuck, 256, 0, stream>>>(bcur, bbuf, x, col, rowbeg, rowend,
                                                 dinv, Xs, N, cap);

    // 2. fused gather1 + GEMM1 + GEMM2 -> Ts (8 waves per 16-row tile)
    int mtiles = (N + 15) / 16;
    gemm_fused_kernel<<<mtiles, 512, 0, stream>>>(rowbeg, rowend, col, Xs,
                                                  W1s, W2s, b1, dinv, Ts, N);

    // 3. gather2 + fused bias/relu -> out
    int gth = N * 32;
    gather2_kernel<<<(gth + 255) / 256, 256, 0, stream>>>(rowbeg, rowend, col, Ts,
                                                          dinv, b2, out, N);
}